// Round 6
// baseline (46.804 us; speedup 1.0000x reference)
//
#include <hip/hip_runtime.h>

// x: [128,8,32,32,32] f32  cw: [16,8,3,3,3] f32  cb: [16]  bias: [16]  out: [128]
// out[b] = (1/6750)*sum_{c,cells} maxpool2(conv_raw) + sum_c(cb[c]/2 + bias[c])
//
// R6: HBM-traffic-minimal design. Block = (b, h-quarter), walks all 15 pd with a
// 6-slab LDS ring (slab = 10 rows x [w32][ci8] bf16, XOR-swizzled). Per step:
// issue next-2-plane loads -> 32x32x16 mfma (N=16co x 2od, K=8ci x 2planes,
// 24 ds_read_b128 : 36 mfma) -> trunc v_perm pack + ds_write -> 1 barrier.
// HBM: 159 MB total (1.19x h-halo only) ~= 25 us floor; compute hides under it.

using short8 = __attribute__((ext_vector_type(8))) short;
using f32x16 = __attribute__((ext_vector_type(16))) float;

__device__ __forceinline__ unsigned short f2bf_rn(float f) {
  unsigned u = __float_as_uint(f);
  return (unsigned short)((u + 0x7FFFu + ((u >> 16) & 1u)) >> 16);
}

// Bp[g=(pb2*3+kh)*3+kw][lane]: 8 bf16; lane: col=l&31 (co=col&15, od=col>>4),
// koff=l>>5; value j: w[co][ci=j][kd=2*pb2+koff-od][kh][kw]; kd outside 0..2 -> 0.
// (verified end-to-end in R4, absmax 0.0)
__global__ __launch_bounds__(256) void prep_w(const float* __restrict__ cw,
                                              short* __restrict__ Bp) {
  int i = threadIdx.x + blockIdx.x * 256;
  if (i >= 1152) return;
  int g = i >> 6, l = i & 63;
  int pb2 = g / 9, kh = (g / 3) % 3, kw = g % 3;
  int col = l & 31, koff = l >> 5;
  int co = col & 15, od = col >> 4;
  int kd = 2 * pb2 + koff - od;
  short8 o;
#pragma unroll
  for (int j = 0; j < 8; ++j) {
    float v = (kd >= 0 && kd <= 2) ? cw[(co * 8 + j) * 27 + kd * 9 + kh * 3 + kw] : 0.0f;
    o[j] = (short)f2bf_rn(v);
  }
  *(short8*)(Bp + (size_t)i * 8) = o;
}

__global__ __launch_bounds__(256, 2) void conv_mfma(const float* __restrict__ x,
                                                    const short* __restrict__ Bp,
                                                    float* __restrict__ partial) {
  __shared__ __align__(16) char lds[6 * 5120];  // 6-slab ring, 30720 B
  __shared__ float red[4];

  const int bid = blockIdx.x;                   // 512 blocks
  const int swz = (bid & 7) * 64 + (bid >> 3);  // XCD-chunk (512%8==0, bijective)
  const int b = swz >> 2, q = swz & 3;          // h-quarter q: ph 4q.. (4 or 3)
  const int t = threadIdx.x, lane = t & 63, wv = t >> 6;
  const int nph = (q == 3) ? 3 : 4;
  const int nrows = (q == 3) ? 8 : 10;          // slab rows staged per plane
  const int row0 = 8 * q;                       // global h of slab row 0
  const int sites = nrows * 8;                  // staging sites per plane
  const float* xb = x + (size_t)b * 262144;

  // ---- staging decode: threads t < 2*sites handle (plane-of-pair, site) ----
  const bool sact = t < 2 * sites;
  const int spl = (t >= sites) ? 1 : 0;
  const int ss = sact ? (t - spl * sites) : 0;
  const int shr = ss >> 3, swc = ss & 7;
  const float* gsite = xb + (row0 + shr) * 32 + swc * 4;  // + d*1024 + ci*32768

  auto issue = [&](int dpair, float4* v) {
    if (!sact) return;
    const float* gp = gsite + (dpair + spl) * 1024;
#pragma unroll
    for (int ci = 0; ci < 8; ++ci) v[ci] = *(const float4*)(gp + ci * 32768);
  };
  auto writeSlab = [&](int dpair, const float4* v) {
    if (!sact) return;
    const int d = dpair + spl;
    char* sb = lds + (d % 6) * 5120 + shr * 512;
#pragma unroll
    for (int wi = 0; wi < 4; ++wi) {
      const int w = swc * 4 + wi;
      uint4 o;  // truncation bf16 pack: [ci0..ci7] via v_perm (hi16 of pairs)
      o.x = __builtin_amdgcn_perm(__float_as_uint(((const float*)&v[1])[wi]),
                                  __float_as_uint(((const float*)&v[0])[wi]), 0x07060302u);
      o.y = __builtin_amdgcn_perm(__float_as_uint(((const float*)&v[3])[wi]),
                                  __float_as_uint(((const float*)&v[2])[wi]), 0x07060302u);
      o.z = __builtin_amdgcn_perm(__float_as_uint(((const float*)&v[5])[wi]),
                                  __float_as_uint(((const float*)&v[4])[wi]), 0x07060302u);
      o.w = __builtin_amdgcn_perm(__float_as_uint(((const float*)&v[7])[wi]),
                                  __float_as_uint(((const float*)&v[6])[wi]), 0x07060302u);
      *(uint4*)(sb + ((w * 16) ^ (((w >> 3) & 3) << 4))) = o;
    }
  };

  // ---- per-lane compute constants ----
  const int ow = lane & 31, koff = lane >> 5;
  int wbv[3];
#pragma unroll
  for (int kw = 0; kw < 3; ++kw) {
    int w = ow + kw; if (w > 31) w = 31;  // clamped lanes' rows are pool-masked
    wbv[kw] = (w * 16) ^ (((w >> 3) & 3) << 4);
  }
  const bool docomp = wv < nph;
  const int rowb = 2 * wv;  // local row base of this wave's oh-pair

  // ---- B fragments (block-invariant) ----
  short8 Bw[18];
#pragma unroll
  for (int g = 0; g < 18; ++g)
    Bw[g] = *(const short8*)(Bp + ((size_t)g * 64 + lane) * 8);

  // ---- prologue: stage planes 0..3 ----
  {
    float4 va[8], vb[8];
    issue(0, va); issue(2, vb);
    writeSlab(0, va); writeSlab(2, vb);
  }
  __syncthreads();

  // ---- main loop over pd ----
  float sum = 0.0f;
  int slot0 = koff, slot1 = 2 + koff;  // slots of planes (2pd+koff), (2pd+2+koff)
  for (int pd = 0; pd < 15; ++pd) {
    const bool more = (pd < 14);
    float4 va[8];
    if (more) issue(2 * pd + 4, va);  // prefetch next plane pair (lat hides under mfma)

    if (docomp) {
      f32x16 C0 = {}, C1 = {};
      const char* p0 = lds + slot0 * 5120 + rowb * 512;
      const char* p1 = lds + slot1 * 5120 + rowb * 512;
#pragma unroll
      for (int j = 0; j < 4; ++j) {  // rolling input-row window
        short8 f[6];
#pragma unroll
        for (int kw = 0; kw < 3; ++kw) {
          f[kw]     = *(const short8*)(p0 + j * 512 + wbv[kw]);
          f[3 + kw] = *(const short8*)(p1 + j * 512 + wbv[kw]);
        }
#pragma unroll
        for (int pb2 = 0; pb2 < 2; ++pb2)
#pragma unroll
          for (int kw = 0; kw < 3; ++kw) {
            if (j < 3)
              C0 = __builtin_amdgcn_mfma_f32_32x32x16_bf16(f[pb2 * 3 + kw],
                     Bw[pb2 * 9 + j * 3 + kw], C0, 0, 0, 0);
            if (j > 0)
              C1 = __builtin_amdgcn_mfma_f32_32x32x16_bf16(f[pb2 * 3 + kw],
                     Bw[pb2 * 9 + (j - 1) * 3 + kw], C1, 0, 0, 0);
          }
      }
      // maxpool 2x2x2: C-row pairs = ow pairs; C0/C1 = oh pair; shfl_xor(16) = od
#pragma unroll
      for (int i = 0; i < 8; ++i) {
        float v = fmaxf(fmaxf(C0[2 * i], C0[2 * i + 1]),
                        fmaxf(C1[2 * i], C1[2 * i + 1]));
        v = fmaxf(v, __shfl_xor(v, 16));
        if (((lane & 31) < 16) && !(koff == 1 && i == 7)) sum += v;  // pw15 invalid
      }
    }

    if (more) writeSlab(2 * pd + 4, va);  // waits vmcnt, packs, writes ring
    __syncthreads();
    slot0 += 2; if (slot0 >= 6) slot0 -= 6;
    slot1 += 2; if (slot1 >= 6) slot1 -= 6;
  }

  // ---- block reduction ----
#pragma unroll
  for (int off = 32; off; off >>= 1) sum += __shfl_down(sum, off);
  if (lane == 0) red[wv] = sum;
  __syncthreads();
  if (t == 0) partial[b * 4 + q] = red[0] + red[1] + red[2] + red[3];
}

__global__ __launch_bounds__(128) void finalize(const float* __restrict__ partial,
                                                const float* __restrict__ cb,
                                                const float* __restrict__ bias,
                                                float* __restrict__ out) {
  const int b = threadIdx.x;  // 128 threads, 1 block
  float k = 0.0f;
#pragma unroll
  for (int c = 0; c < 16; ++c) k += cb[c] * 0.5f + bias[c];
  out[b] = (partial[4 * b] + partial[4 * b + 1] + partial[4 * b + 2] +
            partial[4 * b + 3]) * (1.0f / 6750.0f) + k;
}

extern "C" void kernel_launch(void* const* d_in, const int* in_sizes, int n_in,
                              void* d_out, int out_size, void* d_ws, size_t ws_size,
                              hipStream_t stream) {
  const float* x    = (const float*)d_in[0];
  const float* cw   = (const float*)d_in[1];
  const float* cb   = (const float*)d_in[2];
  const float* bias = (const float*)d_in[3];
  float* out = (float*)d_out;

  short* Bp      = (short*)d_ws;                   // 1152*16 B = 18432 B
  float* partial = (float*)((char*)d_ws + 32768);  // 512 floats

  prep_w<<<5, 256, 0, stream>>>(cw, Bp);
  conv_mfma<<<512, 256, 0, stream>>>(x, Bp, partial);
  finalize<<<1, 128, 0, stream>>>(partial, cb, bias, out);
}

// Round 7
// 42.241 us; speedup vs baseline: 1.1080x; 1.1080x over previous
//
#include <hip/hip_runtime.h>

// x: [128,8,32,32,32] f32  cw: [16,8,3,3,3] f32  cb: [16]  bias: [16]  out: [128]
// out[b] = (1/6750)*sum_{c,cells} maxpool2(conv_raw) + sum_c(cb[c]/2 + bias[c])
//
// R7: 16x16x32 MFMA body (verified R3/R5: Bw[9], cc[od][s], in-lane pooling, no
// shfl in hot loop) on a 6-slab LDS ring walking pd. Block=(b, h-eighth q):
// 6 input rows (4 for q=7), 256 thr, 18.4 KB LDS, VGPR<=128 -> 4 blocks/CU for
// cross-block stage/compute overlap. Staging: float2 x 8ci (16 live VGPRs),
// v_perm truncation pack, XOR swizzle ^((w>>3)&3)<<4 both sides.

using short8 = __attribute__((ext_vector_type(8))) short;
using f32x4  = __attribute__((ext_vector_type(4))) float;

__device__ __forceinline__ unsigned short f2bf_rn(float f) {
  unsigned u = __float_as_uint(f);
  return (unsigned short)((u + 0x7FFFu + ((u >> 16) & 1u)) >> 16);
}

// Bp[g=kd*3+kh][lane]: 8 bf16 = w[co=lane&15][ci=j][kd][kh][kw=lane>>4]; kw==3 -> 0
__global__ __launch_bounds__(256) void prep_w(const float* __restrict__ cw,
                                              short* __restrict__ Bp) {
  int i = threadIdx.x + blockIdx.x * 256;
  if (i >= 576) return;
  int g = i >> 6, l = i & 63;
  int co = l & 15, kw = l >> 4;
  int kd = g / 3, kh = g % 3;
  short8 o;
#pragma unroll
  for (int j = 0; j < 8; ++j) {
    float v = (kw < 3) ? cw[(co * 8 + j) * 27 + kd * 9 + kh * 3 + kw] : 0.0f;
    o[j] = (short)f2bf_rn(v);
  }
  *(short8*)(Bp + (size_t)i * 8) = o;
}

__global__ __launch_bounds__(256, 4) void conv_mfma(const float* __restrict__ x,
                                                    const short* __restrict__ Bp,
                                                    float* __restrict__ partial) {
  __shared__ __align__(16) char lds[6 * 3072];  // 6-slab ring; slab=[r6][w32][ci8] bf16
  __shared__ float red[4];

  const int bid = blockIdx.x;                    // 1024 blocks
  const int swz = (bid & 7) * 128 + (bid >> 3);  // XCD-chunk, bijective
  const int b = swz >> 3, q = swz & 7;           // q: oh rows 4q..4q+3 (q=7: 2 rows)
  const int t = threadIdx.x, lane = t & 63, wv = t >> 6;
  const int nrows = (q == 7) ? 4 : 6;            // staged rows per plane
  const int row0 = 4 * q;
  const int nsite = 2 * nrows * 16;              // 192 / 128
  const float* xb = x + (size_t)b * 262144;

  // ---- staging decode: site = (plane-of-pair, local row, w-group of 2) ----
  const bool sact = t < nsite;
  const int ss = sact ? t : 0;
  const int spl = ss / (nrows * 16);
  const int rem = ss - spl * (nrows * 16);
  const int sr = rem >> 4, swg = rem & 15;
  const float* gsite = xb + (row0 + sr) * 32 + swg * 2;  // + plane*1024 + ci*32768

  auto issue = [&](int dpair, float2* v) {
    if (!sact) return;
    const float* gp = gsite + (dpair + spl) * 1024;
#pragma unroll
    for (int ci = 0; ci < 8; ++ci) v[ci] = *(const float2*)(gp + ci * 32768);
  };
  auto writeSlab = [&](int dpair, const float2* v) {
    if (!sact) return;
    const int d = dpair + spl;
    char* sb = lds + (d % 6) * 3072 + sr * 512;
#pragma unroll
    for (int wi = 0; wi < 2; ++wi) {
      const int w = swg * 2 + wi;
      uint4 o;  // truncation bf16 pack [ci0..ci7] (order verified in R6)
      o.x = __builtin_amdgcn_perm(__float_as_uint(((const float*)&v[1])[wi]),
                                  __float_as_uint(((const float*)&v[0])[wi]), 0x07060302u);
      o.y = __builtin_amdgcn_perm(__float_as_uint(((const float*)&v[3])[wi]),
                                  __float_as_uint(((const float*)&v[2])[wi]), 0x07060302u);
      o.z = __builtin_amdgcn_perm(__float_as_uint(((const float*)&v[5])[wi]),
                                  __float_as_uint(((const float*)&v[4])[wi]), 0x07060302u);
      o.w = __builtin_amdgcn_perm(__float_as_uint(((const float*)&v[7])[wi]),
                                  __float_as_uint(((const float*)&v[6])[wi]), 0x07060302u);
      *(uint4*)(sb + ((w * 16) ^ (((w >> 3) & 3) << 4))) = o;
    }
  };

  // ---- B fragments (9 (kd,kh) groups) ----
  short8 Bw[9];
#pragma unroll
  for (int g = 0; g < 9; ++g)
    Bw[g] = *(const short8*)(Bp + ((size_t)g * 64 + lane) * 8);

  // ---- per-lane A addressing (verified R3): w = m + kw(tg), chunk1 +16 ----
  const int m = lane & 15, tg = lane >> 4;
  const int w0 = m + tg;
  int w1 = m + 16 + tg; if (w1 > 31) w1 = 31;  // clamp hits only masked/pad lanes
  const int wb0 = (w0 * 16) ^ (((w0 >> 3) & 3) << 4);
  const int wb1 = (w1 * 16) ^ (((w1 >> 3) & 3) << 4);

  // ---- task mapping: wave -> (oh-pair op, chunk c) ----
  const bool docomp = (q < 7) || (wv < 2);
  const int op = (q < 7) ? (wv >> 1) : 0;
  const int c  = (q < 7) ? (wv & 1) : wv;
  const int wbase = (c ? wb1 : wb0) + (2 * op) * 512;  // local row lr = 2*op

  // ---- prologue: stage planes 0..3 ----
  {
    float2 va[8], vb[8];
    issue(0, va); issue(2, vb);
    writeSlab(0, va); writeSlab(2, vb);
  }
  __syncthreads();

  // ---- main loop over pd ----
  float sum = 0.0f;
  for (int pd = 0; pd < 15; ++pd) {
    const bool more = (pd < 14);
    float2 va[8];
    if (more) issue(2 * pd + 4, va);  // prefetch next plane pair

    if (docomp) {
      const char* sb0 = lds + ((2 * pd)     % 6) * 3072 + wbase;
      const char* sb1 = lds + ((2 * pd + 1) % 6) * 3072 + wbase;
      const char* sb2 = lds + ((2 * pd + 2) % 6) * 3072 + wbase;
      const char* sb3 = lds + ((2 * pd + 3) % 6) * 3072 + wbase;
      const char* sbp[4] = {sb0, sb1, sb2, sb3};
      f32x4 cc[2][2] = {};  // [od][s]
#pragma unroll
      for (int p = 0; p < 4; ++p) {
#pragma unroll
        for (int rr = 0; rr < 4; ++rr) {
          const short8 a = *(const short8*)(sbp[p] + rr * 512);
          if (p < 3 && rr < 3)
            cc[0][0] = __builtin_amdgcn_mfma_f32_16x16x32_bf16(a, Bw[p * 3 + rr], cc[0][0], 0, 0, 0);
          if (p < 3 && rr > 0)
            cc[0][1] = __builtin_amdgcn_mfma_f32_16x16x32_bf16(a, Bw[p * 3 + rr - 1], cc[0][1], 0, 0, 0);
          if (p > 0 && rr < 3)
            cc[1][0] = __builtin_amdgcn_mfma_f32_16x16x32_bf16(a, Bw[(p - 1) * 3 + rr], cc[1][0], 0, 0, 0);
          if (p > 0 && rr > 0)
            cc[1][1] = __builtin_amdgcn_mfma_f32_16x16x32_bf16(a, Bw[(p - 1) * 3 + rr - 1], cc[1][1], 0, 0, 0);
        }
      }
      // maxpool 2x2x2 fully in-lane (od, s in regs; ow pairs = C row pairs)
#pragma unroll
      for (int p2 = 0; p2 < 2; ++p2) {
        float v = fmaxf(fmaxf(fmaxf(cc[0][0][2 * p2], cc[0][0][2 * p2 + 1]),
                              fmaxf(cc[0][1][2 * p2], cc[0][1][2 * p2 + 1])),
                        fmaxf(fmaxf(cc[1][0][2 * p2], cc[1][0][2 * p2 + 1]),
                              fmaxf(cc[1][1][2 * p2], cc[1][1][2 * p2 + 1])));
        const bool inval = (c == 1) && (tg == 3) && (p2 == 1);  // pw 15 invalid
        sum += inval ? 0.0f : v;
      }
    }

    if (more) writeSlab(2 * pd + 4, va);  // vmcnt wait + pack + ring write
    __syncthreads();
  }

  // ---- block reduction ----
#pragma unroll
  for (int off = 32; off; off >>= 1) sum += __shfl_down(sum, off);
  if (lane == 0) red[wv] = sum;
  __syncthreads();
  if (t == 0) partial[b * 8 + q] = red[0] + red[1] + red[2] + red[3];
}

__global__ __launch_bounds__(128) void finalize(const float* __restrict__ partial,
                                                const float* __restrict__ cb,
                                                const float* __restrict__ bias,
                                                float* __restrict__ out) {
  const int b = threadIdx.x;  // 128 threads, 1 block
  float k = 0.0f;
#pragma unroll
  for (int c = 0; c < 16; ++c) k += cb[c] * 0.5f + bias[c];
  float s = 0.0f;
#pragma unroll
  for (int q = 0; q < 8; ++q) s += partial[b * 8 + q];
  out[b] = s * (1.0f / 6750.0f) + k;
}

extern "C" void kernel_launch(void* const* d_in, const int* in_sizes, int n_in,
                              void* d_out, int out_size, void* d_ws, size_t ws_size,
                              hipStream_t stream) {
  const float* x    = (const float*)d_in[0];
  const float* cw   = (const float*)d_in[1];
  const float* cb   = (const float*)d_in[2];
  const float* bias = (const float*)d_in[3];
  float* out = (float*)d_out;

  short* Bp      = (short*)d_ws;                   // 576*16 B = 9216 B
  float* partial = (float*)((char*)d_ws + 32768);  // 1024 floats

  prep_w<<<3, 256, 0, stream>>>(cw, Bp);
  conv_mfma<<<1024, 256, 0, stream>>>(x, Bp, partial);
  finalize<<<1, 128, 0, stream>>>(partial, cb, bias, out);
}